// Round 8
// baseline (123.059 us; speedup 1.0000x reference)
//
#include <hip/hip_runtime.h>
#include <math.h>

#define NB 2048
#define DEPTH 8

// ws layout (float offsets)
#define FTAB_OFF    0        // sponge fused cs: 8*5*256*8 = 81920 floats
#define BF01_OFF    81920    // bf stages 0-1: 256*3*2 float4 = 6144 floats
#define BFF_OFF     88064    // bf fused (2,3)..(10,11): 5*256*8 = 10240 floats
#define ACT4_OFF    98304    // act table: 2048 float4 = 8192 floats
#define PHYSA_OFF   106496   // int per (d,t)x2: mem scatter addrs (natural), 4096 ints
#define PHYSR_OFF   110592   // recall addrs [2048] int (natural)
#define PHYSO2_OFF  112640   // per-thread pre-gather absolute addrs [256*12] int
// total 115712 floats = 462848 bytes

// Per-row LDS region (floats), natural layout, wave-private:
//   memb [0,2304)   single exchange buf EXB [2304,3328)
// bf tail working buffer overlays [0,3072) after memb/staging are consumed.
#define EXB 2304
#define RSZ 3328   // region size per row

// ---------------- single merged setup dispatch (r5 tables, natural addrs) --------
__global__ void setup_kernel(const float* __restrict__ angles,
                             const float* __restrict__ bf_angles,
                             const float* __restrict__ act_bias,
                             const float* __restrict__ act_curv,
                             const int* __restrict__ recall_idx,
                             const int* __restrict__ out_mem_idx,
                             float* __restrict__ ws) {
    __shared__ int physL[4096];
    __shared__ int rcl[2048];
    __shared__ int oml[2048];
    if (blockIdx.x < 200) {
        int id = blockIdx.x * 256 + threadIdx.x;
        if (id < 40960) {
            // sponge fused table: id = ((d*5+g)*256 + t)*4 + w ; quad a = 2*(t&127)+(t>>7)
            int w = id & 3, t = (id >> 2) & 255, dg = id >> 10;
            int d = dg / 5, g = dg - 5 * d;
            int a = 2 * (t & 127) + (t >> 7);
            int pair = (w == 0) ? a : (w == 1) ? (a + 256)
                     : (w == 2) ? (2 * a) : (2 * a + 1);
            int st = 2 * g + (w >> 1);
            float ang = angles[(d * 10 + st) * 512 + pair];
            float s, c; __sincosf(ang, &s, &c);
            ws[FTAB_OFF + 2 * id]     = c;
            ws[FTAB_OFF + 2 * id + 1] = s;
        } else if (id < 44032) {
            // BF01: e = (t*3+i)*4 + w ; a = t+256i
            int e = id - 40960;
            int w = e & 3; int ti = e >> 2;
            int t = ti / 3; int i = ti - 3 * t;
            int a = t + 256 * i;
            int pair = (w == 0) ? a : (w == 1) ? (a + 768)
                     : (w == 2) ? (2 * a) : (2 * a + 1);
            int stage = (w < 2) ? 0 : 1;
            float ang = bf_angles[stage * 1536 + pair];
            float s, c; __sincosf(ang, &s, &c);
            ws[BF01_OFF + 2 * e]     = c;
            ws[BF01_OFF + 2 * e + 1] = s;
        } else if (id < 49152) {
            // BFF: e = (f*256+t)*4 + w ; fused stages (2+2f, 3+2f)
            int e = id - 44032;
            int f = e >> 10; int rem = e & 1023; int t = rem >> 2; int w = rem & 3;
            int P;
            if (f == 0) P = 3 * t;
            else if (f < 4) { int k = 8 - 2 * f;
                              P = ((t >> (2 * f)) * (768 >> k)) + (t & ((256 >> k) - 1)); }
            else P = t;
            int pair = (w == 0) ? P : (w == 1) ? (P + 768)
                     : (w == 2) ? (2 * P) : (2 * P + 1);
            int stage = (w < 2) ? (2 + 2 * f) : (3 + 2 * f);
            float ang = bf_angles[stage * 1536 + pair];
            float s, c; __sincosf(ang, &s, &c);
            ws[BFF_OFF + 2 * e]     = c;
            ws[BFF_OFF + 2 * e + 1] = s;
        } else if (id < 51200) {
            int ida = id - 49152;              // d*256 + k
            float cu = act_curv[ida];
            float c  = 0.5f * (cu + sqrtf(cu * cu + 1.0f));
            ((float4*)(ws + ACT4_OFF))[ida] =
                make_float4(act_bias[ida], c, 1.0f / c, 0.0f);
        }
    } else {
        // phys block: compacted mem slot allocation (2304 phys slots).
        // Depth-ascending DP in LDS (recall targets at depth d reference only
        // indices < 512*d, so resolving d = 0..7 in order needs no chase).
        int tid = threadIdx.x;
        for (int e = tid; e < 2048; e += 256) rcl[e] = recall_idx[e];
        for (int e = tid; e < 2048; e += 256) oml[e] = out_mem_idx[e];
        for (int e = tid; e < 512; e += 256) physL[e] = e;   // d = 0: p = j
        __syncthreads();
        for (int d = 1; d < 8; ++d) {
            for (int j = tid; j < 512; j += 256) {
                int p;
                if (j < 256) p = 256 + d * 256 + j;
                else          p = physL[rcl[(d - 1) * 256 + (j - 256)]];
                physL[512 * d + j] = p;
            }
            __syncthreads();
        }
        // natural addressing: lds float addr (within region) == phys slot index
        int* pa = (int*)(ws + PHYSA_OFF);
        for (int e = tid; e < 2048; e += 256) {
            int d = e >> 8, t = e & 255;
            int a = 2 * (t & 127) + (t >> 7);
            pa[2 * e]     = physL[d * 512 + 2 * a];
            pa[2 * e + 1] = physL[d * 512 + 2 * a + 1];
        }
        int* pr = (int*)(ws + PHYSR_OFF);
        for (int e = tid; e < 2048; e += 256)
            pr[e] = physL[rcl[e]];
        int* po = (int*)(ws + PHYSO2_OFF);
        for (int e = tid; e < 3072; e += 256) {
            int tt = e / 12; int r = e - 12 * tt; int i = r >> 2; int k = r & 3;
            int a = tt + 256 * i;
            int tl2 = a >> 1, th2 = a & 1;
            int pos = tl2 + 1536 * th2 + 384 * k;
            po[e] = (pos < 2048) ? physL[oml[pos]]
                                 : EXB + (pos - 2048);        // region-relative addr
        }
    }
}

__device__ __forceinline__ float actf(float x, float c, float ic) {
    const float is2 = 0.70710678118654752f;
    float tt = 0.78539816339744831f * ic;
    float y0 = is2 * ic;
    float y1 = (is2 - 1.0f) * ic;
    float mid = ic * (is2 - __cosf(0.78539816339744831f + c * x));
    return x > tt ? (y0 + (x - tt)) : (x < -tt ? y1 : mid);
}

// ---------------- main kernel: 4 wave-private rows per block, ZERO barriers ------
// Each wave owns one row in a private 3328-float LDS region. All cross-lane
// exchange goes through that region; same-wave DS ops are in-order and the
// compiler preserves ds_write->ds_read order for may-aliasing dynamic addrs,
// so no s_barrier and no lgkmcnt(0) drains are needed anywhere. Source order
// enforces the phase constraints (all reads of a phase before the next
// phase's writes). Lane handles 4 virtual threads tq = lane + 64q.
__launch_bounds__(256, 3)
__global__ void sponge_kernel(const float* __restrict__ X,
                              const float* __restrict__ scales,
                              const float* __restrict__ ws,
                              float* __restrict__ out) {
    __shared__ float Lall[4 * RSZ];      // 53248 B -> 3 blocks/CU = 12 waves/CU
    const int lane = threadIdx.x & 63;
    const int wvid = threadIdx.x >> 6;
    float* __restrict__ L = Lall + wvid * RSZ;
    const int row = blockIdx.x * 4 + wvid;

    const float4* bf01  = (const float4*)(ws + BF01_OFF);
    const float4* bff   = (const float4*)(ws + BFF_OFF);
    const float4* act4  = (const float4*)(ws + ACT4_OFF);
    const int2* physA  = (const int2*)(ws + PHYSA_OFF);
    const int*  physr  = (const int*)(ws + PHYSR_OFF);
    const int*  physo2 = (const int*)(ws + PHYSO2_OFF);

    // per-virtual-thread address constants (bit-permutation layout A)
    int Wn[4], Rn[4], Bq[4], Aq[4];
#pragma unroll
    for (int q = 0; q < 4; ++q) {
        int tq = lane + 64 * q;
        int tl = tq & 127, th = tq >> 7;
        Wn[q] = 2 * (tl & 15) + 32 * th + 64 * (tl >> 4);            // A(2a)
        Rn[q] = (tl & 1) + 2 * ((tl >> 2) & 15) + 32 * ((tl >> 1) & 1)
              + 64 * (tl >> 6) + 512 * th;                           // A(b)
        Bq[q] = tl + th * 512;
        Aq[q] = 2 * tl + th;
    }

    float h[4][4];
    {
        const float* Xr = X + (size_t)row * 1024;
#pragma unroll
        for (int q = 0; q < 4; ++q)
#pragma unroll
            for (int k = 0; k < 4; ++k)
                h[q][k] = Xr[Bq[q] + 128 * k] * scales[Bq[q] + 128 * k];
    }

#define DQUAD(cA, cB, i0, i1, i2, i3, F0, F1, F2, F3)                    \
    { float g0 =  (cA).x * (i0) + (cA).y * (i2);                         \
      float g2 = -(cA).y * (i0) + (cA).x * (i2);                         \
      float g1 =  (cA).z * (i1) + (cA).w * (i3);                         \
      float g3 = -(cA).w * (i1) + (cA).z * (i3);                         \
      F0 =  (cB).x * g0 + (cB).y * g1;                                   \
      F2 = -(cB).y * g0 + (cB).x * g1;                                   \
      F1 =  (cB).z * g2 + (cB).w * g3;                                   \
      F3 =  -(cB).w * g2 + (cB).z * g3; }

    const float4* ftab = (const float4*)(ws + FTAB_OFF);
    int fb = 0;
    float4 csA[4], csB[4];
#define LOADC()                                                          \
    { _Pragma("unroll")                                                  \
      for (int q = 0; q < 4; ++q) {                                      \
          int tq = lane + 64 * q;                                        \
          csA[q] = ftab[fb + 2 * tq];                                    \
          csB[q] = ftab[fb + 2 * tq + 1];                                \
      } fb += 512; }
    LOADC();                             // group (0,0); pipelined one ahead below

#pragma unroll 1
    for (int d = 0; d < DEPTH; ++d) {
        // depth metadata (global loads; compiler schedules, no drains anywhere)
        float4 av[2][4]; int pr2[2][2]; int2 pmv[4];
#pragma unroll
        for (int q = 0; q < 2; ++q) {
            int tq = lane + 64 * q;                  // act half: virtual t = tq < 128
            int k0 = tq >> 1;
#pragma unroll
            for (int j = 0; j < 4; ++j) av[q][j] = act4[d * 256 + k0 + 64 * j];
            pr2[q][0] = physr[d * 256 + tq];         // keep half: u = tq
            pr2[q][1] = physr[d * 256 + tq + 128];
        }
#pragma unroll
        for (int q = 0; q < 4; ++q) pmv[q] = physA[d * 256 + lane + 64 * q];

#pragma unroll
        for (int g = 0; g < 4; ++g) {
            float f[4][4];
#pragma unroll
            for (int q = 0; q < 4; ++q)
                DQUAD(csA[q], csB[q], h[q][0], h[q][1], h[q][2], h[q][3],
                      f[q][0], f[q][1], f[q][2], f[q][3]);
#pragma unroll
            for (int q = 0; q < 4; ++q) {
                *(float2*)(L + EXB + Wn[q])       = make_float2(f[q][0], f[q][1]);
                *(float2*)(L + EXB + Wn[q] + 512) = make_float2(f[q][2], f[q][3]);
            }
            LOADC();                     // next group's coeffs fly over the reads
#pragma unroll
            for (int q = 0; q < 4; ++q) {
                h[q][0] = L[EXB + Rn[q]];
                h[q][1] = L[EXB + Rn[q] + 128];
                h[q][2] = L[EXB + Rn[q] + 256];
                h[q][3] = L[EXB + Rn[q] + 384];
            }
        }
        // ---- g == 4: mem scatter + keep + activation + recall ----
        {
            float f[4][4];
#pragma unroll
            for (int q = 0; q < 4; ++q)
                DQUAD(csA[q], csB[q], h[q][0], h[q][1], h[q][2], h[q][3],
                      f[q][0], f[q][1], f[q][2], f[q][3]);
#pragma unroll
            for (int q = 0; q < 4; ++q) {
                L[pmv[q].x] = f[q][0];               // memb scatter (natural addrs)
                L[pmv[q].y] = f[q][1];
                *(float2*)(L + EXB + 2 * Aq[q]) = make_float2(f[q][2], f[q][3]);
            }
            if (d < DEPTH - 1) LOADC();  // next depth's (d+1,0) coeffs
            const float* Z = L + EXB;
#pragma unroll
            for (int q = 0; q < 2; ++q) {            // virtual t < 128: activation
                int tq = lane + 64 * q;
                int k0 = tq >> 1;
                float sgn = (tq & 1) ? -1.0f : 1.0f;
                h[q][0] = actf(sgn * (Z[k0]       + av[q][0].x), av[q][0].y, av[q][0].z);
                h[q][1] = actf(sgn * (Z[k0 + 64]  + av[q][1].x), av[q][1].y, av[q][1].z);
                h[q][2] = actf(sgn * (Z[k0 + 128] + av[q][2].x), av[q][2].y, av[q][2].z);
                h[q][3] = actf(sgn * (Z[k0 + 192] + av[q][3].x), av[q][3].y, av[q][3].z);
            }
#pragma unroll
            for (int q = 0; q < 2; ++q) {            // virtual t >= 128: keep+recall
                int u = lane + 64 * q;
                h[2 + q][0] = Z[256 + u];
                h[2 + q][1] = Z[384 + u];
                h[2 + q][2] = L[pr2[q][0]];
                h[2 + q][3] = L[pr2[q][1]];
            }
        }
    }

    // ---- tail: stage sponge, gather pre, bf network ----
    int4 pga[4][3];
#pragma unroll
    for (int q = 0; q < 4; ++q) {
        const int4* pgp = (const int4*)(physo2 + (lane + 64 * q) * 12);
#pragma unroll
        for (int j = 0; j < 3; ++j) pga[q][j] = pgp[j];
    }
#pragma unroll
    for (int q = 0; q < 4; ++q) {        // stage sponge element e at EXB+e
        L[EXB + Bq[q]]       = h[q][0];
        L[EXB + Bq[q] + 128] = h[q][1];
        L[EXB + Bq[q] + 256] = h[q][2];
        L[EXB + Bq[q] + 384] = h[q][3];
    }
    // gather pre: all 48 reads issued before any bf01 write (source order)
    float w[4][12];
#pragma unroll
    for (int q = 0; q < 4; ++q) {
        int4 pg = pga[q][0];
        w[q][0] = L[pg.x]; w[q][1] = L[pg.y]; w[q][2] = L[pg.z]; w[q][3] = L[pg.w];
        pg = pga[q][1];
        w[q][4] = L[pg.x]; w[q][5] = L[pg.y]; w[q][6] = L[pg.z]; w[q][7] = L[pg.w];
        pg = pga[q][2];
        w[q][8] = L[pg.x]; w[q][9] = L[pg.y]; w[q][10] = L[pg.z]; w[q][11] = L[pg.w];
    }
    // fused stages (0,1): write bf working buffer [0,3072)
#pragma unroll
    for (int q = 0; q < 4; ++q) {
        int tq = lane + 64 * q;
#pragma unroll
        for (int i = 0; i < 3; ++i) {
            float4 c01 = bf01[(tq * 3 + i) * 2];
            float4 c23 = bf01[(tq * 3 + i) * 2 + 1];
            float y0, y1, y2, y3;
            DQUAD(c01, c23, w[q][4 * i], w[q][4 * i + 1], w[q][4 * i + 2], w[q][4 * i + 3],
                  y0, y1, y2, y3);
            *(float2*)(L + 2 * tq + 512 * i)        = make_float2(y0, y1);
            *(float2*)(L + 2 * tq + 512 * i + 1536) = make_float2(y2, y3);
        }
    }
    // fused pruned double-stages (2,3) (4,5) (6,7) (8,9): read-all then write-all
#pragma unroll
    for (int f = 0; f < 4; ++f) {
        float x1[4], x2[4], x3[4], x4[4];
        float4 cS[4], cT[4]; int Pq[4];
#pragma unroll
        for (int q = 0; q < 4; ++q) {
            int tq = lane + 64 * q;
            int P;
            if (f == 0) P = 3 * tq;
            else { const int k = 8 - 2 * f;
                   P = ((tq >> (2 * f)) * (768 >> k)) + (tq & ((256 >> k) - 1)); }
            Pq[q] = P;
            int base = (P >> 1) + (P & 1) * 1536;
            cS[q] = bff[(f * 256 + tq) * 2];
            cT[q] = bff[(f * 256 + tq) * 2 + 1];
            x1[q] = L[base];
            x2[q] = L[base + 384];
            x3[q] = L[base + 768];
            x4[q] = L[base + 1152];
        }
#pragma unroll
        for (int q = 0; q < 4; ++q) {
            float o1P =  cS[q].x * x1[q] + cS[q].y * x3[q];
            float o2P = -cS[q].y * x1[q] + cS[q].x * x3[q];
            float o1Q =  cS[q].z * x2[q] + cS[q].w * x4[q];
            float o2Q = -cS[q].w * x2[q] + cS[q].z * x4[q];
            float y0 =  cT[q].x * o1P + cT[q].y * o1Q;
            float y2 = -cT[q].y * o1P + cT[q].x * o1Q;
            float y1 =  cT[q].z * o2P + cT[q].w * o2Q;
            float y3 = -cT[q].w * o2P + cT[q].z * o2Q;
            *(float2*)(L + 2 * Pq[q])        = make_float2(y0, y1);
            *(float2*)(L + 2 * Pq[q] + 1536) = make_float2(y2, y3);
        }
    }
    // fused (10,11) + output store
#pragma unroll
    for (int q = 0; q < 4; ++q) {
        int tq = lane + 64 * q;
        int base = (tq >> 1) + (tq & 1) * 1536;
        float4 cS = bff[(4 * 256 + tq) * 2];
        float4 cT = bff[(4 * 256 + tq) * 2 + 1];
        float x1 = L[base];
        float x2 = L[base + 384];
        float x3 = L[base + 768];
        float x4 = L[base + 1152];
        float o1P =  cS.x * x1 + cS.y * x3;
        float o2P = -cS.y * x1 + cS.x * x3;
        float o1Q =  cS.z * x2 + cS.w * x4;
        float o2Q = -cS.w * x2 + cS.z * x4;
        *(float2*)(out + (size_t)row * 512 + 2 * tq) =
            make_float2(cT.x * o1P + cT.y * o1Q, cT.z * o2P + cT.w * o2Q);
    }
#undef DQUAD
#undef LOADC
}

extern "C" void kernel_launch(void* const* d_in, const int* in_sizes, int n_in,
                              void* d_out, int out_size, void* d_ws, size_t ws_size,
                              hipStream_t stream) {
    const float* X          = (const float*)d_in[0];
    const float* scales     = (const float*)d_in[1];
    const float* angles     = (const float*)d_in[2];
    const float* act_bias   = (const float*)d_in[3];
    // d_in[4] act_activation — unused by the reference
    const float* act_curv   = (const float*)d_in[5];
    const float* bf_angles  = (const float*)d_in[6];
    // d_in[7] shuffle_perm — structural perfect shuffle, hardcoded
    const int*   recall_idx  = (const int*)d_in[8];
    const int*   out_mem_idx = (const int*)d_in[9];
    // d_in[10] bf_perm — structural perfect shuffle, hardcoded

    float* ws = (float*)d_ws;   // 462848 bytes used

    setup_kernel<<<201, 256, 0, stream>>>(angles, bf_angles, act_bias, act_curv,
                                          recall_idx, out_mem_idx, ws);
    sponge_kernel<<<NB / 4, 256, 0, stream>>>(X, scales, ws, (float*)d_out);
}

// Round 9
// 120.369 us; speedup vs baseline: 1.0223x; 1.0223x over previous
//
#include <hip/hip_runtime.h>
#include <math.h>

#define NB 2048
#define DEPTH 8

// ws layout (float offsets)
#define FTAB_OFF    0        // sponge fused cs: 8*5*256*8 = 81920 floats
#define BF01_OFF    81920    // bf stages 0-1: 256*3*2 float4 = 6144 floats
#define BFF_OFF     88064    // bf fused (2,3)..(10,11): 5*256*8 = 10240 floats
#define ACT4_OFF    98304    // act table: 2048 float4 = 8192 floats
#define PHYSA_OFF   106496   // int per (d,t)x2: mem scatter addrs (natural), 4096 ints
#define PHYSR_OFF   110592   // recall addrs [2048] int (natural)
#define PHYSO2_OFF  112640   // per-thread pre-gather absolute addrs [256*12] int
// total 115712 floats = 462848 bytes

// LDS map (floats), ONE row per 128-thread block:
//   memb natural [0,2304)   exch buf0 [2304,3328)=EXB   exch buf1 [3328,4352)=EXB1
// Exchange buffers use th-bit interleave I(e) = 2*(A(e)&511) + (A(e)>>9): since
// the shuffle's bit-permutation A maps bit9->bit9, a lane's b64 read returns the
// holdings of BOTH its virtual threads (vt0=t, vt1=t+128) -- keeping r2's exact
// b64/b128 op widths and counts for one row. bf tail overlays [0,3072) natural.
#define EXB  2304
#define EXB1 3328

// soft barrier: drain LDS ops only, then barrier (no vmcnt drain -- global
// coeff prefetches stay in flight across workgroup barriers).
#define SBAR() asm volatile("s_waitcnt lgkmcnt(0)\n\ts_barrier" ::: "memory")

// ---------------- single merged setup dispatch (natural tables, as r7) -----------
__global__ void setup_kernel(const float* __restrict__ angles,
                             const float* __restrict__ bf_angles,
                             const float* __restrict__ act_bias,
                             const float* __restrict__ act_curv,
                             const int* __restrict__ recall_idx,
                             const int* __restrict__ out_mem_idx,
                             float* __restrict__ ws) {
    __shared__ int physL[4096];
    __shared__ int rcl[2048];
    __shared__ int oml[2048];
    if (blockIdx.x < 200) {
        int id = blockIdx.x * 256 + threadIdx.x;
        if (id < 40960) {
            // sponge fused table: id = ((d*5+g)*256 + t)*4 + w ; quad a = 2*(t&127)+(t>>7)
            int w = id & 3, t = (id >> 2) & 255, dg = id >> 10;
            int d = dg / 5, g = dg - 5 * d;
            int a = 2 * (t & 127) + (t >> 7);
            int pair = (w == 0) ? a : (w == 1) ? (a + 256)
                     : (w == 2) ? (2 * a) : (2 * a + 1);
            int st = 2 * g + (w >> 1);
            float ang = angles[(d * 10 + st) * 512 + pair];
            float s, c; __sincosf(ang, &s, &c);
            ws[FTAB_OFF + 2 * id]     = c;
            ws[FTAB_OFF + 2 * id + 1] = s;
        } else if (id < 44032) {
            // BF01: e = (t*3+i)*4 + w ; a = t+256i
            int e = id - 40960;
            int w = e & 3; int ti = e >> 2;
            int t = ti / 3; int i = ti - 3 * t;
            int a = t + 256 * i;
            int pair = (w == 0) ? a : (w == 1) ? (a + 768)
                     : (w == 2) ? (2 * a) : (2 * a + 1);
            int stage = (w < 2) ? 0 : 1;
            float ang = bf_angles[stage * 1536 + pair];
            float s, c; __sincosf(ang, &s, &c);
            ws[BF01_OFF + 2 * e]     = c;
            ws[BF01_OFF + 2 * e + 1] = s;
        } else if (id < 49152) {
            // BFF: e = (f*256+t)*4 + w ; fused stages (2+2f, 3+2f)
            int e = id - 44032;
            int f = e >> 10; int rem = e & 1023; int t = rem >> 2; int w = rem & 3;
            int P;
            if (f == 0) P = 3 * t;
            else if (f < 4) { int k = 8 - 2 * f;
                              P = ((t >> (2 * f)) * (768 >> k)) + (t & ((256 >> k) - 1)); }
            else P = t;
            int pair = (w == 0) ? P : (w == 1) ? (P + 768)
                     : (w == 2) ? (2 * P) : (2 * P + 1);
            int stage = (w < 2) ? (2 + 2 * f) : (3 + 2 * f);
            float ang = bf_angles[stage * 1536 + pair];
            float s, c; __sincosf(ang, &s, &c);
            ws[BFF_OFF + 2 * e]     = c;
            ws[BFF_OFF + 2 * e + 1] = s;
        } else if (id < 51200) {
            int ida = id - 49152;              // d*256 + k
            float cu = act_curv[ida];
            float c  = 0.5f * (cu + sqrtf(cu * cu + 1.0f));
            ((float4*)(ws + ACT4_OFF))[ida] =
                make_float4(act_bias[ida], c, 1.0f / c, 0.0f);
        }
    } else {
        // phys block: compacted mem slot allocation (2304 phys slots).
        // Depth-ascending DP in LDS (recall targets at depth d reference only
        // indices < 512*d, so resolving d = 0..7 in order needs no chase).
        int tid = threadIdx.x;
        for (int e = tid; e < 2048; e += 256) rcl[e] = recall_idx[e];
        for (int e = tid; e < 2048; e += 256) oml[e] = out_mem_idx[e];
        for (int e = tid; e < 512; e += 256) physL[e] = e;   // d = 0: p = j
        __syncthreads();
        for (int d = 1; d < 8; ++d) {
            for (int j = tid; j < 512; j += 256) {
                int p;
                if (j < 256) p = 256 + d * 256 + j;
                else          p = physL[rcl[(d - 1) * 256 + (j - 256)]];
                physL[512 * d + j] = p;
            }
            __syncthreads();
        }
        // natural addressing: lds float addr == phys slot index
        int* pa = (int*)(ws + PHYSA_OFF);
        for (int e = tid; e < 2048; e += 256) {
            int d = e >> 8, t = e & 255;
            int a = 2 * (t & 127) + (t >> 7);
            pa[2 * e]     = physL[d * 512 + 2 * a];
            pa[2 * e + 1] = physL[d * 512 + 2 * a + 1];
        }
        int* pr = (int*)(ws + PHYSR_OFF);
        for (int e = tid; e < 2048; e += 256)
            pr[e] = physL[rcl[e]];
        int* po = (int*)(ws + PHYSO2_OFF);
        for (int e = tid; e < 3072; e += 256) {
            int tt = e / 12; int r = e - 12 * tt; int i = r >> 2; int k = r & 3;
            int a = tt + 256 * i;
            int tl2 = a >> 1, th2 = a & 1;
            int pos = tl2 + 1536 * th2 + 384 * k;
            po[e] = (pos < 2048) ? physL[oml[pos]]
                                 : EXB + (pos - 2048);        // stage-buffer addr
        }
    }
}

__device__ __forceinline__ float actf(float x, float c, float ic) {
    const float is2 = 0.70710678118654752f;
    float tt = 0.78539816339744831f * ic;
    float y0 = is2 * ic;
    float y1 = (is2 - 1.0f) * ic;
    float mid = ic * (is2 - __cosf(0.78539816339744831f + c * x));
    return x > tt ? (y0 + (x - tt)) : (x < -tt ? y1 : mid);
}

// ---------------- main kernel: 1 row per 128-thread block (2-wave domains) -------
// r2's exact op widths/counts via th-bit interleave; 8 blocks/CU = 16 waves/CU,
// all 2048 blocks resident; barrier domains are 2 waves instead of 4.
__launch_bounds__(128, 4)
__global__ void sponge_kernel(const float* __restrict__ X,
                              const float* __restrict__ scales,
                              const float* __restrict__ ws,
                              float* __restrict__ out) {
    __shared__ float L[4352];            // 17408 B -> 8 blocks/CU
    const int t = threadIdx.x;           // [0,128); vt0 = t, vt1 = t + 128
    const int row = blockIdx.x;

    const float4* bf01  = (const float4*)(ws + BF01_OFF);
    const float4* bff   = (const float4*)(ws + BFF_OFF);
    const float4* act4  = (const float4*)(ws + ACT4_OFF);
    const int2* physA  = (const int2*)(ws + PHYSA_OFF);
    const int*  physr  = (const int*)(ws + PHYSR_OFF);
    const int*  physo2 = (const int*)(ws + PHYSO2_OFF);

    // I-layout addr consts: vt0 quad a0=2t -> A(2a0)=Wb0 (th=0); vt1 at Wb0+32.
    // b128 write covers I addrs 2Wb0..2Wb0+3 = (f0, f2, f1, f3) of one vt.
    const int WX = 4 * (t & 15) + 128 * (t >> 4);     // = 2*Wb0; vt1 at +64
    const int RX = 2 * ((t & 1) + 2 * ((t >> 2) & 15) + 32 * ((t >> 1) & 1)
                      + 64 * (t >> 6));               // b64 read base; +256m

    float h0[4], h1[4];                  // vt0 / vt1 holdings
    {
        const float* Xr = X + (size_t)row * 1024;
#pragma unroll
        for (int m = 0; m < 4; ++m) {
            h0[m] = Xr[t + 128 * m]       * scales[t + 128 * m];
            h1[m] = Xr[t + 512 + 128 * m] * scales[t + 512 + 128 * m];
        }
    }

#define DQUAD(cA, cB, i0, i1, i2, i3, F0, F1, F2, F3)                    \
    { float g0 =  (cA).x * (i0) + (cA).y * (i2);                         \
      float g2 = -(cA).y * (i0) + (cA).x * (i2);                         \
      float g1 =  (cA).z * (i1) + (cA).w * (i3);                         \
      float g3 = -(cA).w * (i1) + (cA).z * (i3);                         \
      F0 =  (cB).x * g0 + (cB).y * g1;                                   \
      F2 = -(cB).y * g0 + (cB).x * g1;                                   \
      F1 =  (cB).z * g2 + (cB).w * g3;                                   \
      F3 = -(cB).w * g2 + (cB).z * g3; }

    int woff = EXB, roff = EXB1;
    const float4* ft = (const float4*)(ws + FTAB_OFF) + 2 * t;
    float4 cA0 = ft[0], cB0 = ft[1];     // vt0 coeffs, group (0,0)
    float4 cA1 = ft[256], cB1 = ft[257]; // vt1 coeffs (virtual t+128)
    int4 pg0a, pg0b, pg0c, pg1a, pg1b, pg1c;   // tail gather addrs (d==7)

    for (int d = 0; d < DEPTH; ++d) {
        float4 a0, a1, a2, a3;           // act params (vt0), loaded at g==3
        int r0 = 0, r1 = 0;              // recall addrs (vt1), loaded at g==3
        int2 pm0, pm1;                   // mem scatter addrs, loaded at g==2
#pragma unroll
        for (int g = 0; g < 4; ++g) {
            float f00, f01, f02, f03, f10, f11, f12, f13;
            DQUAD(cA0, cB0, h0[0], h0[1], h0[2], h0[3], f00, f01, f02, f03);
            DQUAD(cA1, cB1, h1[0], h1[1], h1[2], h1[3], f10, f11, f12, f13);
            // I-layout: one b128 per vt (order f0, f2, f1, f3)
            *(float4*)(L + woff + WX)      = make_float4(f00, f02, f01, f03);
            *(float4*)(L + woff + WX + 64) = make_float4(f10, f12, f11, f13);
            { int tmp = woff; woff = roff; roff = tmp; }
            ft += 512;                       // next group's coeffs: in flight
            float4 nA0 = ft[0], nB0 = ft[1];
            float4 nA1 = ft[256], nB1 = ft[257];
            if (g == 2) { pm0 = physA[d * 256 + t]; pm1 = physA[d * 256 + t + 128]; }
            if (g == 3) {
                int k0 = t >> 1;
                a0 = act4[d * 256 + k0];       a1 = act4[d * 256 + k0 + 64];
                a2 = act4[d * 256 + k0 + 128]; a3 = act4[d * 256 + k0 + 192];
                r0 = physr[d * 256 + t];       r1 = physr[d * 256 + t + 128];
            }
            SBAR();
            // b64 read returns (vt0, vt1) holding m
            float2 e0 = *(const float2*)(L + roff + RX);
            float2 e1 = *(const float2*)(L + roff + RX + 256);
            float2 e2 = *(const float2*)(L + roff + RX + 512);
            float2 e3 = *(const float2*)(L + roff + RX + 768);
            h0[0] = e0.x; h1[0] = e0.y; h0[1] = e1.x; h1[1] = e1.y;
            h0[2] = e2.x; h1[2] = e2.y; h0[3] = e3.x; h1[3] = e3.y;
            cA0 = nA0; cB0 = nB0; cA1 = nA1; cB1 = nB1;
        }
        // ---- g == 4: mem scatter + keep + activation + recall ----
        {
            float f00, f01, f02, f03, f10, f11, f12, f13;
            DQUAD(cA0, cB0, h0[0], h0[1], h0[2], h0[3], f00, f01, f02, f03);
            DQUAD(cA1, cB1, h1[0], h1[1], h1[2], h1[3], f10, f11, f12, f13);
            // mem half: b32 scatter into natural memb
            L[pm0.x] = f00; L[pm0.y] = f01;
            L[pm1.x] = f10; L[pm1.y] = f11;
            // sponge half -> natural Z at z{4t..4t+3}: one b128
            *(float4*)(L + woff + 4 * t) = make_float4(f02, f03, f12, f13);
            { int tmp = woff; woff = roff; roff = tmp; }
            ft += 512;                       // next depth's coeffs (benign overread at d==7)
            float4 nA0 = ft[0], nB0 = ft[1];
            float4 nA1 = ft[256], nB1 = ft[257];
            if (d == DEPTH - 1) {            // tail gather addrs: covered by act phase
                const int4* p0 = (const int4*)(physo2 + t * 12);
                const int4* p1 = (const int4*)(physo2 + (t + 128) * 12);
                pg0a = p0[0]; pg0b = p0[1]; pg0c = p0[2];
                pg1a = p1[0]; pg1b = p1[1]; pg1c = p1[2];
            }
            SBAR();                  // Z + mem scatter visible (LDS only)
            const float* Z = L + roff;
            // vt0 = virtual t < 128: activation (per-lane, no wave divergence)
            int k0 = t >> 1;
            float sgn = (t & 1) ? -1.0f : 1.0f;
            h0[0] = actf(sgn * (Z[k0]       + a0.x), a0.y, a0.z);
            h0[1] = actf(sgn * (Z[k0 + 64]  + a1.x), a1.y, a1.z);
            h0[2] = actf(sgn * (Z[k0 + 128] + a2.x), a2.y, a2.z);
            h0[3] = actf(sgn * (Z[k0 + 192] + a3.x), a3.y, a3.z);
            // vt1 = virtual t >= 128: keep + recall (u = t)
            h1[0] = Z[256 + t]; h1[1] = Z[384 + t];
            h1[2] = L[r0];      h1[3] = L[r1];
            cA0 = nA0; cB0 = nB0; cA1 = nA1; cB1 = nB1;
        }
    }

    // ---- tail: hoist bf01 coeffs, stage sponge natural at EXB (woff==EXB) ----
    float4 c0a[3], c0b[3], c1a[3], c1b[3];
#pragma unroll
    for (int i = 0; i < 3; ++i) {
        c0a[i] = bf01[(t * 3 + i) * 2];         c0b[i] = bf01[(t * 3 + i) * 2 + 1];
        c1a[i] = bf01[((t + 128) * 3 + i) * 2]; c1b[i] = bf01[((t + 128) * 3 + i) * 2 + 1];
    }
#pragma unroll
    for (int m = 0; m < 4; ++m) {
        L[EXB + t + 128 * m]       = h0[m];     // elements e = t + 128m
        L[EXB + 512 + t + 128 * m] = h1[m];     // elements e = 512 + t + 128m
    }
    SBAR();

    // ---- gather pre: 12 b32 loads per vt (absolute natural addrs) ----
    float w0[12], w1[12];
    w0[0] = L[pg0a.x]; w0[1] = L[pg0a.y]; w0[2]  = L[pg0a.z]; w0[3]  = L[pg0a.w];
    w0[4] = L[pg0b.x]; w0[5] = L[pg0b.y]; w0[6]  = L[pg0b.z]; w0[7]  = L[pg0b.w];
    w0[8] = L[pg0c.x]; w0[9] = L[pg0c.y]; w0[10] = L[pg0c.z]; w0[11] = L[pg0c.w];
    w1[0] = L[pg1a.x]; w1[1] = L[pg1a.y]; w1[2]  = L[pg1a.z]; w1[3]  = L[pg1a.w];
    w1[4] = L[pg1b.x]; w1[5] = L[pg1b.y]; w1[6]  = L[pg1b.z]; w1[7]  = L[pg1b.w];
    w1[8] = L[pg1c.x]; w1[9] = L[pg1c.y]; w1[10] = L[pg1c.z]; w1[11] = L[pg1c.w];
    // f=0 bff coeffs: in flight across the barrier
    float4 cS0 = bff[t * 2],         cT0 = bff[t * 2 + 1];
    float4 cS1 = bff[(t + 128) * 2], cT1 = bff[(t + 128) * 2 + 1];
    SBAR();                              // all reads done before overwrite

    // ---- fused stages (0,1); working buffer = natural [0,3072) ----
#pragma unroll
    for (int i = 0; i < 3; ++i) {
        float y0, y1, y2, y3;
        DQUAD(c0a[i], c0b[i], w0[4 * i], w0[4 * i + 1], w0[4 * i + 2], w0[4 * i + 3],
              y0, y1, y2, y3);
        *(float2*)(L + 2 * t + 512 * i)        = make_float2(y0, y1);
        *(float2*)(L + 2 * t + 512 * i + 1536) = make_float2(y2, y3);
        DQUAD(c1a[i], c1b[i], w1[4 * i], w1[4 * i + 1], w1[4 * i + 2], w1[4 * i + 3],
              y0, y1, y2, y3);
        *(float2*)(L + 2 * t + 256 + 512 * i)        = make_float2(y0, y1);
        *(float2*)(L + 2 * t + 256 + 512 * i + 1536) = make_float2(y2, y3);
    }
    SBAR();

    // ---- fused pruned double-stages (2,3) (4,5) (6,7) (8,9), coeffs pipelined ----
#pragma unroll
    for (int f = 0; f < 4; ++f) {
        int P0, P1;
        if (f == 0) { P0 = 3 * t; P1 = 3 * (t + 128); }
        else { const int k = 8 - 2 * f;
               P0 = ((t >> (2 * f)) * (768 >> k)) + (t & ((256 >> k) - 1));
               P1 = (((t + 128) >> (2 * f)) * (768 >> k)) + ((t + 128) & ((256 >> k) - 1)); }
        int b0 = (P0 >> 1) + (P0 & 1) * 1536;
        int b1 = (P1 >> 1) + (P1 & 1) * 1536;
        float x10 = L[b0], x20 = L[b0 + 384], x30 = L[b0 + 768], x40 = L[b0 + 1152];
        float x11 = L[b1], x21 = L[b1 + 384], x31 = L[b1 + 768], x41 = L[b1 + 1152];
        // vt0
        float o1P =  cS0.x * x10 + cS0.y * x30;
        float o2P = -cS0.y * x10 + cS0.x * x30;
        float o1Q =  cS0.z * x20 + cS0.w * x40;
        float o2Q = -cS0.w * x20 + cS0.z * x40;
        float y00 =  cT0.x * o1P + cT0.y * o1Q;
        float y02 = -cT0.y * o1P + cT0.x * o1Q;
        float y01 =  cT0.z * o2P + cT0.w * o2Q;
        float y03 = -cT0.w * o2P + cT0.z * o2Q;
        // vt1
        o1P =  cS1.x * x11 + cS1.y * x31;
        o2P = -cS1.y * x11 + cS1.x * x31;
        o1Q =  cS1.z * x21 + cS1.w * x41;
        o2Q = -cS1.w * x21 + cS1.z * x41;
        float y10 =  cT1.x * o1P + cT1.y * o1Q;
        float y12 = -cT1.y * o1P + cT1.x * o1Q;
        float y11 =  cT1.z * o2P + cT1.w * o2Q;
        float y13 = -cT1.w * o2P + cT1.z * o2Q;
        // next stage's coeffs: in flight across the two barriers below
        float4 nS0 = bff[((f + 1) * 256 + t) * 2];
        float4 nT0 = bff[((f + 1) * 256 + t) * 2 + 1];
        float4 nS1 = bff[((f + 1) * 256 + t + 128) * 2];
        float4 nT1 = bff[((f + 1) * 256 + t + 128) * 2 + 1];
        SBAR();
        *(float2*)(L + 2 * P0)        = make_float2(y00, y01);
        *(float2*)(L + 2 * P0 + 1536) = make_float2(y02, y03);
        *(float2*)(L + 2 * P1)        = make_float2(y10, y11);
        *(float2*)(L + 2 * P1 + 1536) = make_float2(y12, y13);
        SBAR();
        cS0 = nS0; cT0 = nT0; cS1 = nS1; cT1 = nT1;
    }

    // ---- fused (10,11) + output store (coeffs already in cS*/cT*) ----
    {
        int b0 = (t >> 1) + (t & 1) * 1536;
        int b1 = b0 + 64;                // ((t+128)>>1) = (t>>1)+64, parity same
        float x10 = L[b0], x20 = L[b0 + 384], x30 = L[b0 + 768], x40 = L[b0 + 1152];
        float x11 = L[b1], x21 = L[b1 + 384], x31 = L[b1 + 768], x41 = L[b1 + 1152];
        float o1P =  cS0.x * x10 + cS0.y * x30;
        float o2P = -cS0.y * x10 + cS0.x * x30;
        float o1Q =  cS0.z * x20 + cS0.w * x40;
        float o2Q = -cS0.w * x20 + cS0.z * x40;
        *(float2*)(out + (size_t)row * 512 + 2 * t) =
            make_float2(cT0.x * o1P + cT0.y * o1Q, cT0.z * o2P + cT0.w * o2Q);
        o1P =  cS1.x * x11 + cS1.y * x31;
        o2P = -cS1.y * x11 + cS1.x * x31;
        o1Q =  cS1.z * x21 + cS1.w * x41;
        o2Q = -cS1.w * x21 + cS1.z * x41;
        *(float2*)(out + (size_t)row * 512 + 2 * t + 256) =
            make_float2(cT1.x * o1P + cT1.y * o1Q, cT1.z * o2P + cT1.w * o2Q);
    }
#undef DQUAD
}

extern "C" void kernel_launch(void* const* d_in, const int* in_sizes, int n_in,
                              void* d_out, int out_size, void* d_ws, size_t ws_size,
                              hipStream_t stream) {
    const float* X          = (const float*)d_in[0];
    const float* scales     = (const float*)d_in[1];
    const float* angles     = (const float*)d_in[2];
    const float* act_bias   = (const float*)d_in[3];
    // d_in[4] act_activation — unused by the reference
    const float* act_curv   = (const float*)d_in[5];
    const float* bf_angles  = (const float*)d_in[6];
    // d_in[7] shuffle_perm — structural perfect shuffle, hardcoded
    const int*   recall_idx  = (const int*)d_in[8];
    const int*   out_mem_idx = (const int*)d_in[9];
    // d_in[10] bf_perm — structural perfect shuffle, hardcoded

    float* ws = (float*)d_ws;   // 462848 bytes used

    setup_kernel<<<201, 256, 0, stream>>>(angles, bf_angles, act_bias, act_curv,
                                          recall_idx, out_mem_idx, ws);
    sponge_kernel<<<NB, 128, 0, stream>>>(X, scales, ws, (float*)d_out);
}

// Round 11
// 114.166 us; speedup vs baseline: 1.0779x; 1.0543x over previous
//
#include <hip/hip_runtime.h>
#include <math.h>

#define NB 2048
#define DEPTH 8

// ws layout (float offsets)
#define FTAB_OFF    0        // sponge fused cs: 8*5*256*8 = 81920 floats
#define BF01_OFF    81920    // bf stages 0-1: 256*3*2 float4 = 6144 floats
#define BFF_OFF     88064    // bf fused (2,3)..(10,11): 5*256*8 = 10240 floats
#define ACT4_OFF    98304    // act table: 2048 float4 = 8192 floats
#define PHYSA_OFF   106496   // int2 per (d,t): interleaved mem scatter addrs, 4096 ints
#define PHYSR_OFF   110592   // interleaved recall addrs [2048] int
#define PHYSO2_OFF  112640   // per-thread pre-gather absolute addrs [256*12] int
// total 115712 floats = 462848 bytes

// LDS map (floats): memb interleaved [0,4608); exch buf0 [4608,6656); buf1 [6656,8704)
#define MB0 4608
#define MB1 6656

// soft barrier: drain LDS ops only, then barrier. Avoids __syncthreads'
// vmcnt(0) drain so global prefetches (coeffs/act/physr/gather addrs)
// stay in flight across workgroup barriers. All producer->consumer deps
// at these barriers are DS ops, so lgkmcnt(0) is sufficient.
#define SBAR() asm volatile("s_waitcnt lgkmcnt(0)\n\ts_barrier" ::: "memory")

// ---------------- single merged setup dispatch ----------------
__global__ void setup_kernel(const float* __restrict__ angles,
                             const float* __restrict__ bf_angles,
                             const float* __restrict__ act_bias,
                             const float* __restrict__ act_curv,
                             const int* __restrict__ recall_idx,
                             const int* __restrict__ out_mem_idx,
                             float* __restrict__ ws) {
    __shared__ int physL[4096];
    __shared__ int rcl[2048];
    __shared__ int oml[2048];
    if (blockIdx.x < 200) {
        int id = blockIdx.x * 256 + threadIdx.x;
        if (id < 40960) {
            // sponge fused table: id = ((d*5+g)*256 + t)*4 + w ; quad a = 2*(t&127)+(t>>7)
            int w = id & 3, t = (id >> 2) & 255, dg = id >> 10;
            int d = dg / 5, g = dg - 5 * d;
            int a = 2 * (t & 127) + (t >> 7);
            int pair = (w == 0) ? a : (w == 1) ? (a + 256)
                     : (w == 2) ? (2 * a) : (2 * a + 1);
            int st = 2 * g + (w >> 1);
            float ang = angles[(d * 10 + st) * 512 + pair];
            float s, c; __sincosf(ang, &s, &c);
            ws[FTAB_OFF + 2 * id]     = c;
            ws[FTAB_OFF + 2 * id + 1] = s;
        } else if (id < 44032) {
            // BF01: e = (t*3+i)*4 + w ; a = t+256i
            int e = id - 40960;
            int w = e & 3; int ti = e >> 2;
            int t = ti / 3; int i = ti - 3 * t;
            int a = t + 256 * i;
            int pair = (w == 0) ? a : (w == 1) ? (a + 768)
                     : (w == 2) ? (2 * a) : (2 * a + 1);
            int stage = (w < 2) ? 0 : 1;
            float ang = bf_angles[stage * 1536 + pair];
            float s, c; __sincosf(ang, &s, &c);
            ws[BF01_OFF + 2 * e]     = c;
            ws[BF01_OFF + 2 * e + 1] = s;
        } else if (id < 49152) {
            // BFF: e = (f*256+t)*4 + w ; fused stages (2+2f, 3+2f)
            int e = id - 44032;
            int f = e >> 10; int rem = e & 1023; int t = rem >> 2; int w = rem & 3;
            int P;
            if (f == 0) P = 3 * t;
            else if (f < 4) { int k = 8 - 2 * f;
                              P = ((t >> (2 * f)) * (768 >> k)) + (t & ((256 >> k) - 1)); }
            else P = t;
            int pair = (w == 0) ? P : (w == 1) ? (P + 768)
                     : (w == 2) ? (2 * P) : (2 * P + 1);
            int stage = (w < 2) ? (2 + 2 * f) : (3 + 2 * f);
            float ang = bf_angles[stage * 1536 + pair];
            float s, c; __sincosf(ang, &s, &c);
            ws[BFF_OFF + 2 * e]     = c;
            ws[BFF_OFF + 2 * e + 1] = s;
        } else if (id < 51200) {
            int ida = id - 49152;              // d*256 + k
            float cu = act_curv[ida];
            float c  = 0.5f * (cu + sqrtf(cu * cu + 1.0f));
            ((float4*)(ws + ACT4_OFF))[ida] =
                make_float4(act_bias[ida], c, 1.0f / c, 0.0f);
        }
    } else {
        // phys block: compacted mem slot allocation (2304 phys slots).
        // Depth-ascending DP in LDS (recall targets at depth d reference only
        // indices < 512*d, so resolving d = 0..7 in order needs no chase).
        int tid = threadIdx.x;
        for (int e = tid; e < 2048; e += 256) rcl[e] = recall_idx[e];
        for (int e = tid; e < 2048; e += 256) oml[e] = out_mem_idx[e];
        for (int e = tid; e < 512; e += 256) physL[e] = e;   // d = 0: p = j
        __syncthreads();
        for (int d = 1; d < 8; ++d) {
            for (int j = tid; j < 512; j += 256) {
                int p;
                if (j < 256) p = 256 + d * 256 + j;
                else          p = physL[rcl[(d - 1) * 256 + (j - 256)]];
                physL[512 * d + j] = p;
            }
            __syncthreads();
        }
        int* pa = (int*)(ws + PHYSA_OFF);
        for (int e = tid; e < 2048; e += 256) {
            int d = e >> 8, t = e & 255;
            int a = 2 * (t & 127) + (t >> 7);
            pa[2 * e]     = 2 * physL[d * 512 + 2 * a];       // interleaved addr
            pa[2 * e + 1] = 2 * physL[d * 512 + 2 * a + 1];
        }
        int* pr = (int*)(ws + PHYSR_OFF);
        for (int e = tid; e < 2048; e += 256)
            pr[e] = 2 * physL[rcl[e]];                        // interleaved addr
        int* po = (int*)(ws + PHYSO2_OFF);
        for (int e = tid; e < 3072; e += 256) {
            int tt = e / 12; int r = e - 12 * tt; int i = r >> 2; int k = r & 3;
            int a = tt + 256 * i;
            int tl2 = a >> 1, th2 = a & 1;
            int pos = tl2 + 1536 * th2 + 384 * k;
            po[e] = (pos < 2048) ? 2 * physL[oml[pos]]
                                 : MB0 + 2 * (pos - 2048);    // absolute lds addr
        }
    }
}

__device__ __forceinline__ float actf(float x, float c, float ic) {
    const float is2 = 0.70710678118654752f;
    float tt = 0.78539816339744831f * ic;
    float y0 = is2 * ic;
    float y1 = (is2 - 1.0f) * ic;
    float mid = ic * (is2 - __cosf(0.78539816339744831f + c * x));
    return x > tt ? (y0 + (x - tt)) : (x < -tt ? y1 : mid);
}

// ---------------- main kernel: 2 rows per block, row-interleaved LDS ---------------
__launch_bounds__(256, 4)
__global__ void sponge_kernel(const float* __restrict__ X,
                              const float* __restrict__ scales,
                              const float* __restrict__ ws,
                              float* __restrict__ out) {
    __shared__ float L[8704];            // 34816 B -> 4 blocks/CU
    const int t = threadIdx.x;
    const int rowA = blockIdx.x * 2;

    const float4* bf01  = (const float4*)(ws + BF01_OFF);
    const float4* bff   = (const float4*)(ws + BFF_OFF);
    const float4* act4  = (const float4*)(ws + ACT4_OFF);
    const int2* physA  = (const int2*)(ws + PHYSA_OFF);
    const int*  physr  = (const int*)(ws + PHYSR_OFF);
    const int*  physo2 = (const int*)(ws + PHYSO2_OFF);

    const int tl = t & 127, th = t >> 7;
    const int b  = tl + th * 512;        // holdings {b+128m}; quad a = 2tl+th
    const int a  = 2 * tl + th;
    // bit-permutation layout A: A0=p0, A1..A4=p2..p5, A5=p1, A6..A9=p6..p9
    const int Wb = 2 * (tl & 15) + 32 * th + 64 * (tl >> 4);    // A(2a)
    const int Rb = (tl & 1) + 2 * ((tl >> 2) & 15) + 32 * ((tl >> 1) & 1)
                 + 64 * (tl >> 6) + 512 * th;                   // A(b)
    const int WI = 2 * Wb;               // b128 write base (interleaved)
    const int RI = 2 * Rb;               // b64 read base, +256m
    const int u  = t - 128;

    float hA0, hA1, hA2, hA3, hB0, hB1, hB2, hB3;
    {
        const float* Xr0 = X + (size_t)rowA * 1024;
        const float* Xr1 = Xr0 + 1024;
        float s0 = scales[b],       s1 = scales[b + 128];
        float s2 = scales[b + 256], s3 = scales[b + 384];
        hA0 = Xr0[b] * s0; hA1 = Xr0[b + 128] * s1;
        hA2 = Xr0[b + 256] * s2; hA3 = Xr0[b + 384] * s3;
        hB0 = Xr1[b] * s0; hB1 = Xr1[b + 128] * s1;
        hB2 = Xr1[b + 256] * s2; hB3 = Xr1[b + 384] * s3;
    }

    int woff = MB0, roff = MB1;
    const float4* ft = (const float4*)(ws + FTAB_OFF) + 2 * t;
    float4 csA = ft[0], csB = ft[1];     // group (0,0); pipelined one ahead below

#define DQUAD(cA, cB, i0, i1, i2, i3, F0, F1, F2, F3)                    \
    { float g0 =  (cA).x * (i0) + (cA).y * (i2);                         \
      float g2 = -(cA).y * (i0) + (cA).x * (i2);                         \
      float g1 =  (cA).z * (i1) + (cA).w * (i3);                         \
      float g3 = -(cA).w * (i1) + (cA).z * (i3);                         \
      F0 =  (cB).x * g0 + (cB).y * g1;                                   \
      F2 = -(cB).y * g0 + (cB).x * g1;                                   \
      F1 =  (cB).z * g2 + (cB).w * g3;                                   \
      F3 = -(cB).w * g2 + (cB).z * g3; }

    for (int d = 0; d < DEPTH; ++d) {
        for (int g = 0; g < 5; ++g) {
            float fA0, fA1, fA2, fA3, fB0, fB1, fB2, fB3;
            DQUAD(csA, csB, hA0, hA1, hA2, hA3, fA0, fA1, fA2, fA3);
            DQUAD(csA, csB, hB0, hB1, hB2, hB3, fB0, fB1, fB2, fB3);
            if (g < 4) {
                // logical {2a,2a+1} both rows -> contiguous b128; {2a+512,2a+513} at +1024
                *(float4*)(L + woff + WI)        = make_float4(fA0, fB0, fA1, fB1);
                *(float4*)(L + woff + WI + 1024) = make_float4(fA2, fB2, fA3, fB3);
                { int tmp = woff; woff = roff; roff = tmp; }
                ft += 512;                       // prefetch next group's coeffs:
                float4 nA = ft[0], nB = ft[1];   // in flight across the barrier
                SBAR();
                float2 e0 = *(const float2*)(L + roff + RI);
                float2 e1 = *(const float2*)(L + roff + RI + 256);
                float2 e2 = *(const float2*)(L + roff + RI + 512);
                float2 e3 = *(const float2*)(L + roff + RI + 768);
                hA0 = e0.x; hB0 = e0.y; hA1 = e1.x; hB1 = e1.y;
                hA2 = e2.x; hB2 = e2.y; hA3 = e3.x; hB3 = e3.y;
                csA = nA; csB = nB;
            } else {
                // mem half (2a,2a+1): b64 scatter into interleaved memb
                int2 pm = physA[d * 256 + t];
                *(float2*)(L + pm.x) = make_float2(fA0, fB0);
                *(float2*)(L + pm.y) = make_float2(fA1, fB1);
                // sponge half -> natural interleaved Z at zpos {2a, 2a+1}: b128 at 4a
                *(float4*)(L + woff + 4 * a) = make_float4(fA2, fB2, fA3, fB3);
                { int tmp = woff; woff = roff; roff = tmp; }
                ft += 512;                       // next depth's (d+1,0) coeffs
                float4 nA = ft[0], nB = ft[1];   // (last iter reads into BF01 tab: benign)
                // prefetch before barrier (wave-aligned split)
                int r0 = 0, r1 = 0;
                float4 a0, a1, a2, a3;
                if (t < 128) {
                    int k0 = t >> 1;
                    a0 = act4[d * 256 + k0];
                    a1 = act4[d * 256 + k0 + 64];
                    a2 = act4[d * 256 + k0 + 128];
                    a3 = act4[d * 256 + k0 + 192];
                } else {
                    r0 = physr[d * 256 + u];
                    r1 = physr[d * 256 + u + 128];
                }
                SBAR();                  // Z + mem scatter visible (LDS only)
                const float* Z = L + roff;
                if (t < 128) {
                    int k0 = t >> 1;
                    float sgn = (t & 1) ? -1.0f : 1.0f;
                    float2 z0 = *(const float2*)(Z + 2 * k0);
                    float2 z1 = *(const float2*)(Z + 2 * k0 + 128);
                    float2 z2 = *(const float2*)(Z + 2 * k0 + 256);
                    float2 z3 = *(const float2*)(Z + 2 * k0 + 384);
                    hA0 = actf(sgn * (z0.x + a0.x), a0.y, a0.z);
                    hB0 = actf(sgn * (z0.y + a0.x), a0.y, a0.z);
                    hA1 = actf(sgn * (z1.x + a1.x), a1.y, a1.z);
                    hB1 = actf(sgn * (z1.y + a1.x), a1.y, a1.z);
                    hA2 = actf(sgn * (z2.x + a2.x), a2.y, a2.z);
                    hB2 = actf(sgn * (z2.y + a2.x), a2.y, a2.z);
                    hA3 = actf(sgn * (z3.x + a3.x), a3.y, a3.z);
                    hB3 = actf(sgn * (z3.y + a3.x), a3.y, a3.z);
                } else {
                    // keep: zpos {256+u, 384+u}
                    float2 k0v = *(const float2*)(Z + 512 + 2 * u);
                    float2 k1v = *(const float2*)(Z + 768 + 2 * u);
                    float2 rc0 = *(const float2*)(L + r0);
                    float2 rc1 = *(const float2*)(L + r1);
                    hA0 = k0v.x; hB0 = k0v.y;
                    hA1 = k1v.x; hB1 = k1v.y;
                    hA2 = rc0.x; hB2 = rc0.y;
                    hA3 = rc1.x; hB3 = rc1.y;
                }
                csA = nA; csB = nB;
            }
        }
    }

    // ---- prefetch gather addrs, then stage sponge into natural layout at MB0 ----
    int4 pg0, pg1, pg2;
    {
        const int4* pgp = (const int4*)(physo2 + t * 12);
        pg0 = pgp[0]; pg1 = pgp[1]; pg2 = pgp[2];
    }
    *(float2*)(L + MB0 + 2 * b)       = make_float2(hA0, hB0);
    *(float2*)(L + MB0 + 2 * b + 256) = make_float2(hA1, hB1);
    *(float2*)(L + MB0 + 2 * b + 512) = make_float2(hA2, hB2);
    *(float2*)(L + MB0 + 2 * b + 768) = make_float2(hA3, hB3);
    SBAR();

    // ---- gather pre: 12 b64 loads (absolute addrs), both rows at once ----
    float2 w0, w1, w2, w3, w4, w5, w6, w7, w8, w9, w10, w11;
    w0 = *(const float2*)(L + pg0.x); w1 = *(const float2*)(L + pg0.y);
    w2 = *(const float2*)(L + pg0.z); w3 = *(const float2*)(L + pg0.w);
    w4 = *(const float2*)(L + pg1.x); w5 = *(const float2*)(L + pg1.y);
    w6 = *(const float2*)(L + pg1.z); w7 = *(const float2*)(L + pg1.w);
    w8 = *(const float2*)(L + pg2.x); w9 = *(const float2*)(L + pg2.y);
    w10 = *(const float2*)(L + pg2.z); w11 = *(const float2*)(L + pg2.w);
    SBAR();                              // all reads done before overwrite

    // ---- fused stages (0,1) in registers; final buffer = interleaved [0,6144) ----
#define BF01_STEP(i, q0, q1, q2, q3)                                                \
    {                                                                               \
        float4 c01 = bf01[(t * 3 + (i)) * 2];                                       \
        float4 c23 = bf01[(t * 3 + (i)) * 2 + 1];                                   \
        float yA0, yA1, yA2, yA3, yB0, yB1, yB2, yB3;                               \
        DQUAD(c01, c23, q0.x, q1.x, q2.x, q3.x, yA0, yA1, yA2, yA3);                \
        DQUAD(c01, c23, q0.y, q1.y, q2.y, q3.y, yB0, yB1, yB2, yB3);                \
        *(float4*)(L + 4 * t + 1024 * (i))        = make_float4(yA0, yB0, yA1, yB1);\
        *(float4*)(L + 4 * t + 1024 * (i) + 3072) = make_float4(yA2, yB2, yA3, yB3);\
    }
    BF01_STEP(0, w0, w1, w2, w3)
    BF01_STEP(1, w4, w5, w6, w7)
    BF01_STEP(2, w8, w9, w10, w11)
#undef BF01_STEP
    SBAR();

    // ---- fused pruned double-stages (2,3) (4,5) (6,7) (8,9) ----
#pragma unroll
    for (int f = 0; f < 4; ++f) {
        int P;
        if (f == 0) P = 3 * t;
        else { const int k = 8 - 2 * f;
               P = ((t >> (2 * f)) * (768 >> k)) + (t & ((256 >> k) - 1)); }
        int base = 2 * ((P >> 1) + (P & 1) * 1536);
        float4 csS = bff[(f * 256 + t) * 2];
        float4 csT = bff[(f * 256 + t) * 2 + 1];
        float2 x1p = *(const float2*)(L + base);
        float2 x1q = *(const float2*)(L + base + 768);
        float2 x2p = *(const float2*)(L + base + 1536);
        float2 x2q = *(const float2*)(L + base + 2304);
        float o1P =  csS.x * x1p.x + csS.y * x2p.x;
        float o2P = -csS.y * x1p.x + csS.x * x2p.x;
        float o1Q =  csS.z * x1q.x + csS.w * x2q.x;
        float o2Q = -csS.w * x1q.x + csS.z * x2q.x;
        float yA0 =  csT.x * o1P + csT.y * o1Q;
        float yA2 = -csT.y * o1P + csT.x * o1Q;
        float yA1 =  csT.z * o2P + csT.w * o2Q;
        float yA3 = -csT.w * o2P + csT.z * o2Q;
        o1P =  csS.x * x1p.y + csS.y * x2p.y;
        o2P = -csS.y * x1p.y + csS.x * x2p.y;
        o1Q =  csS.z * x1q.y + csS.w * x2q.y;
        o2Q = -csS.w * x1q.y + csS.z * x2q.y;
        float yB0 =  csT.x * o1P + csT.y * o1Q;
        float yB2 = -csT.y * o1P + csT.x * o1Q;
        float yB1 =  csT.z * o2P + csT.w * o2Q;
        float yB3 = -csT.w * o2P + csT.z * o2Q;
        SBAR();
        *(float4*)(L + 4 * P)        = make_float4(yA0, yB0, yA1, yB1);
        *(float4*)(L + 4 * P + 3072) = make_float4(yA2, yB2, yA3, yB3);
        SBAR();
    }

    // ---- fused (10,11) + output store, both rows ----
    {
        int base = 2 * ((t >> 1) + (t & 1) * 1536);
        float4 csS = bff[(4 * 256 + t) * 2];
        float4 csT = bff[(4 * 256 + t) * 2 + 1];
        float2 x1p = *(const float2*)(L + base);
        float2 x1q = *(const float2*)(L + base + 768);
        float2 x2p = *(const float2*)(L + base + 1536);
        float2 x2q = *(const float2*)(L + base + 2304);
        float o1P =  csS.x * x1p.x + csS.y * x2p.x;
        float o2P = -csS.y * x1p.x + csS.x * x2p.x;
        float o1Q =  csS.z * x1q.x + csS.w * x2q.x;
        float o2Q = -csS.w * x1q.x + csS.z * x2q.x;
        *(float2*)(out + (size_t)rowA * 512 + 2 * t) =
            make_float2(csT.x * o1P + csT.y * o1Q, csT.z * o2P + csT.w * o2Q);
        o1P =  csS.x * x1p.y + csS.y * x2p.y;
        o2P = -csS.y * x1p.y + csS.x * x2p.y;
        o1Q =  csS.z * x1q.y + csS.w * x2q.y;
        o2Q = -csS.w * x1q.y + csS.z * x2q.y;
        *(float2*)(out + (size_t)(rowA + 1) * 512 + 2 * t) =
            make_float2(csT.x * o1P + csT.y * o1Q, csT.z * o2P + csT.w * o2Q);
    }
#undef DQUAD
}

extern "C" void kernel_launch(void* const* d_in, const int* in_sizes, int n_in,
                              void* d_out, int out_size, void* d_ws, size_t ws_size,
                              hipStream_t stream) {
    const float* X          = (const float*)d_in[0];
    const float* scales     = (const float*)d_in[1];
    const float* angles     = (const float*)d_in[2];
    const float* act_bias   = (const float*)d_in[3];
    // d_in[4] act_activation — unused by the reference
    const float* act_curv   = (const float*)d_in[5];
    const float* bf_angles  = (const float*)d_in[6];
    // d_in[7] shuffle_perm — structural perfect shuffle, hardcoded
    const int*   recall_idx  = (const int*)d_in[8];
    const int*   out_mem_idx = (const int*)d_in[9];
    // d_in[10] bf_perm — structural perfect shuffle, hardcoded

    float* ws = (float*)d_ws;   // 462848 bytes used

    setup_kernel<<<201, 256, 0, stream>>>(angles, bf_angles, act_bias, act_curv,
                                          recall_idx, out_mem_idx, ws);
    sponge_kernel<<<NB / 2, 256, 0, stream>>>(X, scales, ws, (float*)d_out);
}